// Round 10
// baseline (829.166 us; speedup 1.0000x reference)
//
#include <hip/hip_runtime.h>
#include <hip/hip_bf16.h>
#include <stdint.h>

// Problem constants
#define BB 8
#define SS 2048
#define DD 512
#define NCAT 1024
#define NLAB 8192

typedef short bf16x8 __attribute__((ext_vector_type(8)));
typedef short bf16x4_t __attribute__((ext_vector_type(4)));
typedef float f32x4 __attribute__((ext_vector_type(4)));

#define BAR() do { asm volatile("" ::: "memory"); __builtin_amdgcn_s_barrier(); asm volatile("" ::: "memory"); } while (0)

__device__ __forceinline__ unsigned short f2bf(float f) {
  union { float f; unsigned int u; } v; v.f = f;
  unsigned int u = v.u;
  return (unsigned short)((u + 0x7fffu + ((u >> 16) & 1u)) >> 16);
}
__device__ __forceinline__ float bf2f(unsigned short h) {
  union { unsigned int u; float f; } v; v.u = ((unsigned int)h) << 16;
  return v.f;
}

__device__ __forceinline__ void gload_lds16(const void* g, void* l) {
  __builtin_amdgcn_global_load_lds(
      (const __attribute__((address_space(1))) unsigned int*)g,
      (__attribute__((address_space(3))) unsigned int*)l, 16, 0, 0);
}

// ===========================================================================
// QK GEMM, 8-phase deep pipeline: E[b] = A @ Bc[b]^T  (fused softmax stats)
// KK=512 : plain bf16 NT (E2 path), A row stride 512.
// KK=1536: 3-term split (E1 path): B = [Kh|Kl|Kh], A = [Q1h|Q1l] stride 1024,
//          A-block map kt<32 ? kt&15 : kt-16  ->  Qh*Kh + Qh*Kl + Ql*Kh.
// 256x256 tile, BK=32, 8 waves (2Mx4N), 3-buffer LDS rotation, counted
// vmcnt(4), T2 swizzle, T5 setprio.
// ===========================================================================
template<int KK>
__global__ __launch_bounds__(512, 2) void gemm_qk(
    const short* __restrict__ A, long sA,   // batch stride in elements (0 = shared)
    const short* __restrict__ Bc,           // [B][SS][KK] bf16
    float* __restrict__ E, float* __restrict__ pm, float* __restrict__ ps,
    int M)
{
  constexpr int NK = KK / 32;
  constexpr int AS = (KK == 512) ? 512 : 1024;   // A row stride
  __shared__ __align__(16) char lds[3 * 32768];  // 3 bufs x (A 16KB + B 16KB)
  const int t = threadIdx.x;
  const int w = t >> 6, lane = t & 63;
  const int r = lane & 15, g = lane >> 4;
  const int wm = w >> 2, wn = w & 3;            // 2 x 4 wave grid
  const int m0 = blockIdx.x * 256, n0 = blockIdx.y * 256;
  const int b = blockIdx.z;
  const short* Ab = A + (long)b * sA;
  const short* Bb = Bc + (long)b * SS * KK;

  int offA[8], offB[4];
#pragma unroll
  for (int i = 0; i < 8; ++i) {
    int row = wm * 128 + i * 16 + r;
    int grp = row >> 1, slot = ((row & 1) << 2) | g;
    offA[i] = grp * 128 + (slot ^ (grp & 7)) * 16;
  }
#pragma unroll
  for (int j = 0; j < 4; ++j) {
    int row = wn * 64 + j * 16 + r;
    int grp = row >> 1, slot = ((row & 1) << 2) | g;
    offB[j] = grp * 128 + (slot ^ (grp & 7)) * 16;
  }

  // staging source coords (inverse swizzle; LDS dest stays linear)
  int srow[2], scol[2];
#pragma unroll
  for (int ld = 0; ld < 2; ++ld) {
    int ch = ld * 512 + t;
    int grp = ch >> 3, sl2 = (ch & 7) ^ (grp & 7);
    srow[ld] = grp * 2 + (sl2 >> 2);
    scol[ld] = (sl2 & 3) * 8;
  }

  auto stageA = [&](int kt, int buf) {
    const int ab = (KK == 512) ? kt : (kt < 32 ? (kt & 15) : (kt - 16));
    const long kb = (long)ab * 32;
#pragma unroll
    for (int ld = 0; ld < 2; ++ld)
      gload_lds16(Ab + (long)(m0 + srow[ld]) * AS + kb + scol[ld],
                  lds + buf * 32768 + (ld * 512 + t) * 16);
  };
  auto stageB = [&](int kt, int buf) {
    const long kb = (long)(kt * 32);
#pragma unroll
    for (int ld = 0; ld < 2; ++ld)
      gload_lds16(Bb + (long)(n0 + srow[ld]) * KK + kb + scol[ld],
                  lds + buf * 32768 + 16384 + (ld * 512 + t) * 16);
  };

  f32x4 acc[8][4] = {};

  // prologue: stage K-tiles 0,1; wait tile 0 (vmcnt(4): tile 1 stays in flight)
  stageA(0, 0); stageB(0, 0);
  stageA(1, 1); stageB(1, 1);
  asm volatile("s_waitcnt vmcnt(4)" ::: "memory");
  BAR();

  int cur = 0;
#pragma unroll 1
  for (int kt = 0; kt < NK; ++kt) {
    const char* bA = lds + cur * 32768;
    const char* bB = bA + 16384;
    const int nxt = (cur == 0) ? 2 : cur - 1;  // (kt+2)%3

    bf16x8 av[4], av2[4], bv[4];
    // -------- phase A: reads + stage-A --------
#pragma unroll
    for (int j = 0; j < 4; ++j) bv[j] = *(const bf16x8*)(bB + offB[j]);
#pragma unroll
    for (int i = 0; i < 4; ++i) av[i] = *(const bf16x8*)(bA + offA[i]);
    if (kt + 2 < NK) stageA(kt + 2, nxt);
    BAR();
    __builtin_amdgcn_s_setprio(1);
#pragma unroll
    for (int i = 0; i < 4; ++i)
#pragma unroll
      for (int j = 0; j < 4; ++j)
        acc[i][j] = __builtin_amdgcn_mfma_f32_16x16x32_bf16(av[i], bv[j], acc[i][j], 0, 0, 0);
    __builtin_amdgcn_s_setprio(0);
    BAR();
    // -------- phase B: reads + stage-B --------
#pragma unroll
    for (int i = 0; i < 4; ++i) av2[i] = *(const bf16x8*)(bA + offA[4 + i]);
    if (kt + 2 < NK) stageB(kt + 2, nxt);
    BAR();
    __builtin_amdgcn_s_setprio(1);
#pragma unroll
    for (int i = 0; i < 4; ++i)
#pragma unroll
      for (int j = 0; j < 4; ++j)
        acc[4 + i][j] = __builtin_amdgcn_mfma_f32_16x16x32_bf16(av2[i], bv[j], acc[4 + i][j], 0, 0, 0);
    __builtin_amdgcn_s_setprio(0);
    // -------- boundary: tile kt+1 must have landed --------
    if (kt < NK - 1) {
      if (kt == NK - 2) asm volatile("s_waitcnt vmcnt(0)" ::: "memory");
      else              asm volatile("s_waitcnt vmcnt(4)" ::: "memory");
    }
    BAR();
    cur = (cur == 2) ? 0 : cur + 1;
  }

  // C write
  float* Cg = E + (long)b * M * SS;
#pragma unroll
  for (int i = 0; i < 8; ++i)
#pragma unroll
    for (int j = 0; j < 4; ++j) {
      const int col = n0 + wn * 64 + j * 16 + r;
#pragma unroll
      for (int q = 0; q < 4; ++q) {
        const int row = m0 + wm * 128 + i * 16 + g * 4 + q;
        Cg[(long)row * SS + col] = acc[i][j][q];
      }
    }

  // barrier before reusing LDS for stats
  BAR();

  // fused partial softmax stats over this block's 256 cols
  float* smax = (float*)lds;            // [256][4]
  float* ssum = (float*)(lds + 4096);
#pragma unroll
  for (int i = 0; i < 8; ++i)
#pragma unroll
    for (int q = 0; q < 4; ++q) {
      float mm = fmaxf(fmaxf(acc[i][0][q], acc[i][1][q]),
                       fmaxf(acc[i][2][q], acc[i][3][q]));
#pragma unroll
      for (int off = 1; off <= 8; off <<= 1) mm = fmaxf(mm, __shfl_xor(mm, off, 64));
      float s = 0.f;
#pragma unroll
      for (int j = 0; j < 4; ++j) s += __expf(acc[i][j][q] - mm);
#pragma unroll
      for (int off = 1; off <= 8; off <<= 1) s += __shfl_xor(s, off, 64);
      if (r == 0) {
        const int rowt = wm * 128 + i * 16 + g * 4 + q;   // 0..255
        smax[rowt * 4 + wn] = mm;
        ssum[rowt * 4 + wn] = s;
      }
    }
  BAR();
  if (t < 256) {
    float m0_ = smax[t * 4 + 0], m1_ = smax[t * 4 + 1];
    float m2_ = smax[t * 4 + 2], m3_ = smax[t * 4 + 3];
    float mm = fmaxf(fmaxf(m0_, m1_), fmaxf(m2_, m3_));
    float s = ssum[t * 4 + 0] * __expf(m0_ - mm) + ssum[t * 4 + 1] * __expf(m1_ - mm)
            + ssum[t * 4 + 2] * __expf(m2_ - mm) + ssum[t * 4 + 3] * __expf(m3_ - mm);
    const long base = ((long)b * M + m0 + t) * 8 + (n0 >> 8);
    pm[base] = mm;
    ps[base] = s;
  }
}

// ===========================================================================
// PV GEMM, 8-phase deep pipeline: C[b] = P[b] (Mx2048) @ VT[b] (512x2048)^T
// P generated on the fly from E f32 + global stats (reg-staged A, swizzled
// ds_write placed after phase-B MFMA). Used for C1 (M=1024) and C2 (M=8192).
// ===========================================================================
__global__ __launch_bounds__(512, 2) void gemm_pv(
    const float* __restrict__ E, const float2* __restrict__ stats,
    const short* __restrict__ VT, float* __restrict__ C, int M)
{
  __shared__ __align__(16) char lds[3 * 32768];
  const int t = threadIdx.x;
  const int w = t >> 6, lane = t & 63;
  const int r = lane & 15, g = lane >> 4;
  const int wm = w >> 2, wn = w & 3;
  const int m0 = blockIdx.x * 256, n0 = blockIdx.y * 256;
  const int b = blockIdx.z;
  const float* Eb = E + (long)b * M * SS;
  const short* Bb = VT + (long)b * DD * SS;

  int offA[8], offB[4];
#pragma unroll
  for (int i = 0; i < 8; ++i) {
    int row = wm * 128 + i * 16 + r;
    int grp = row >> 1, slot = ((row & 1) << 2) | g;
    offA[i] = grp * 128 + (slot ^ (grp & 7)) * 16;
  }
#pragma unroll
  for (int j = 0; j < 4; ++j) {
    int row = wn * 64 + j * 16 + r;
    int grp = row >> 1, slot = ((row & 1) << 2) | g;
    offB[j] = grp * 128 + (slot ^ (grp & 7)) * 16;
  }

  // B staging source coords (inverse swizzle; LDS dest linear)
  int srow[2], scol[2];
#pragma unroll
  for (int ld = 0; ld < 2; ++ld) {
    int ch = ld * 512 + t;
    int grp = ch >> 3, sl2 = (ch & 7) ^ (grp & 7);
    srow[ld] = grp * 2 + (sl2 >> 2);
    scol[ld] = (sl2 & 3) * 8;
  }

  // A staging: thread owns row = t>>1, 16 cols starting at (t&1)*16
  const int arow = t >> 1;
  const int ac0 = (t & 1) * 16;
  int wbyte[2];
  {
    const int grp = arow >> 1, cc0 = ac0 >> 3;
#pragma unroll
    for (int ld = 0; ld < 2; ++ld) {
      const int slot = ((arow & 1) << 2) | (cc0 + ld);
      wbyte[ld] = grp * 128 + (slot ^ (grp & 7)) * 16;
    }
  }
  const float2 st = stats[(long)b * M + m0 + arow];
  const float* asrc = Eb + (long)(m0 + arow) * SS + ac0;

  float areg[16];
  auto loadA = [&](int kt) {
    const float* src = asrc + kt * 32;
#pragma unroll
    for (int u = 0; u < 4; ++u)
      *(f32x4*)(areg + u * 4) = *(const f32x4*)(src + u * 4);
  };
  auto writeA = [&](int buf) {
    char* dst = lds + buf * 32768;
#pragma unroll
    for (int ld = 0; ld < 2; ++ld) {
      bf16x8 p;
#pragma unroll
      for (int q = 0; q < 8; ++q)
        p[q] = (short)f2bf(__expf(areg[ld * 8 + q] - st.x) * st.y);
      *(bf16x8*)(dst + wbyte[ld]) = p;
    }
  };
  auto stageB = [&](int kt, int buf) {
    const long kb = (long)(kt * 32);
#pragma unroll
    for (int ld = 0; ld < 2; ++ld)
      gload_lds16(Bb + (long)(n0 + srow[ld]) * SS + kb + scol[ld],
                  lds + buf * 32768 + 16384 + (ld * 512 + t) * 16);
  };

  f32x4 acc[8][4] = {};

  // prologue: tiles 0,1 (A via regs+ds_write, B via gload_lds)
  loadA(0); stageB(0, 0); writeA(0);
  loadA(1); stageB(1, 1); writeA(1);
  asm volatile("s_waitcnt lgkmcnt(0)" ::: "memory");
  BAR();

  int cur = 0;
#pragma unroll 1
  for (int kt = 0; kt < 64; ++kt) {
    const char* bA = lds + cur * 32768;
    const char* bB = bA + 16384;
    const int nxt = (cur == 0) ? 2 : cur - 1;  // (kt+2)%3

    bf16x8 av[4], av2[4], bv[4];
    // -------- phase A: reads + loadA(kt+2) to regs --------
#pragma unroll
    for (int j = 0; j < 4; ++j) bv[j] = *(const bf16x8*)(bB + offB[j]);
#pragma unroll
    for (int i = 0; i < 4; ++i) av[i] = *(const bf16x8*)(bA + offA[i]);
    if (kt + 2 < 64) loadA(kt + 2);
    BAR();
    __builtin_amdgcn_s_setprio(1);
#pragma unroll
    for (int i = 0; i < 4; ++i)
#pragma unroll
      for (int j = 0; j < 4; ++j)
        acc[i][j] = __builtin_amdgcn_mfma_f32_16x16x32_bf16(av[i], bv[j], acc[i][j], 0, 0, 0);
    __builtin_amdgcn_s_setprio(0);
    BAR();
    // -------- phase B: reads + stage-B --------
#pragma unroll
    for (int i = 0; i < 4; ++i) av2[i] = *(const bf16x8*)(bA + offA[4 + i]);
    if (kt + 2 < 64) stageB(kt + 2, nxt);
    BAR();
    __builtin_amdgcn_s_setprio(1);
#pragma unroll
    for (int i = 0; i < 4; ++i)
#pragma unroll
      for (int j = 0; j < 4; ++j)
        acc[4 + i][j] = __builtin_amdgcn_mfma_f32_16x16x32_bf16(av2[i], bv[j], acc[4 + i][j], 0, 0, 0);
    __builtin_amdgcn_s_setprio(0);
    if (kt + 2 < 64) writeA(nxt);   // exp+cvt+ds_write into freed buffer
    // -------- boundary --------
    if (kt == 62) asm volatile("s_waitcnt vmcnt(0)" ::: "memory");
    asm volatile("s_waitcnt lgkmcnt(0)" ::: "memory");
    BAR();
    cur = (cur == 2) ? 0 : cur + 1;
  }

  float* Cg = C + (long)b * M * DD;
#pragma unroll
  for (int i = 0; i < 8; ++i)
#pragma unroll
    for (int j = 0; j < 4; ++j) {
      const int col = n0 + wn * 64 + j * 16 + r;
#pragma unroll
      for (int q = 0; q < 4; ++q) {
        const int row = m0 + wm * 128 + i * 16 + g * 4 + q;
        Cg[(long)row * DD + col] = acc[i][j][q];
      }
    }
}

// ---------------------------------------------------------------------------
// Split-bf16 NT GEMM (3-term): C = A*B^T, acc += Al*Bh + Ah*Bl + Ah*Bh.
// WQCAT=1: also write split bf16 [hi|lo] (row stride 1024) for rows < NCAT.
// 128x128 tile, BK=32, 4 waves.
// ---------------------------------------------------------------------------
template<int BIAS, int WQCAT>
__global__ __launch_bounds__(256) void gemm_nt_split(
    const short* __restrict__ Ah, const short* __restrict__ Al,
    const short* __restrict__ Bh, const short* __restrict__ Bl,
    float* __restrict__ C, short* __restrict__ Qcat, const float* __restrict__ bias,
    int M, int N, int K)
{
  __shared__ short AsH[128 * 32];
  __shared__ short AsL[128 * 32];
  __shared__ short BsH[128 * 32];
  __shared__ short BsL[128 * 32];
  const int t = threadIdx.x, w = t >> 6, l = t & 63;
  const int r = l & 15, g = l >> 4;
  const int m0 = blockIdx.x * 128, n0 = blockIdx.y * 128;
  const int wm = (w >> 1) * 64, wn = (w & 1) * 64;
  const int srow = t >> 2, scol = (t & 3) * 8;

  f32x4 acc[4][4] = {};

  const int nk = K >> 5;
  for (int kt = 0; kt < nk; ++kt) {
    const long k0 = (long)(kt << 5);
    const long ga0 = (long)(m0 + srow) * K + k0 + scol;
    const long ga1 = (long)(m0 + srow + 64) * K + k0 + scol;
    const long gb0 = (long)(n0 + srow) * K + k0 + scol;
    const long gb1 = (long)(n0 + srow + 64) * K + k0 + scol;
    gload_lds16(Ah + ga0, &AsH[w * 512]);
    gload_lds16(Ah + ga1, &AsH[2048 + w * 512]);
    gload_lds16(Bh + gb0, &BsH[w * 512]);
    gload_lds16(Bh + gb1, &BsH[2048 + w * 512]);
    gload_lds16(Al + ga0, &AsL[w * 512]);
    gload_lds16(Al + ga1, &AsL[2048 + w * 512]);
    gload_lds16(Bl + gb0, &BsL[w * 512]);
    gload_lds16(Bl + gb1, &BsL[2048 + w * 512]);
    __syncthreads();
    bf16x8 ah[4], al_[4], bh[4], bl_[4];
#pragma unroll
    for (int i = 0; i < 4; ++i) {
      ah[i]  = *(const bf16x8*)&AsH[(wm + i * 16 + r) * 32 + g * 8];
      bh[i]  = *(const bf16x8*)&BsH[(wn + i * 16 + r) * 32 + g * 8];
      al_[i] = *(const bf16x8*)&AsL[(wm + i * 16 + r) * 32 + g * 8];
      bl_[i] = *(const bf16x8*)&BsL[(wn + i * 16 + r) * 32 + g * 8];
    }
#pragma unroll
    for (int i = 0; i < 4; ++i)
#pragma unroll
      for (int j = 0; j < 4; ++j) {
        acc[i][j] = __builtin_amdgcn_mfma_f32_16x16x32_bf16(al_[i], bh[j], acc[i][j], 0, 0, 0);
        acc[i][j] = __builtin_amdgcn_mfma_f32_16x16x32_bf16(ah[i], bl_[j], acc[i][j], 0, 0, 0);
        acc[i][j] = __builtin_amdgcn_mfma_f32_16x16x32_bf16(ah[i], bh[j], acc[i][j], 0, 0, 0);
      }
    __syncthreads();
  }

#pragma unroll
  for (int i = 0; i < 4; ++i)
#pragma unroll
    for (int j = 0; j < 4; ++j) {
      f32x4 v = acc[i][j];
      const int col = n0 + wn + j * 16 + r;
      float bv = 0.f;
      if (BIAS) bv = bias[col];
#pragma unroll
      for (int q = 0; q < 4; ++q) {
        const int row = m0 + wm + i * 16 + g * 4 + q;
        const float val = v[q] + bv;
        C[(long)row * N + col] = val;
        if (WQCAT && row < NCAT) {
          unsigned short h = f2bf(val);
          Qcat[(long)row * 1024 + col] = (short)h;
          Qcat[(long)row * 1024 + 512 + col] = (short)f2bf(val - bf2f(h));
        }
      }
    }
}

// combine per-256col partials (8 per row) into per-row (max, 1/sum)
__global__ __launch_bounds__(256) void stats_combine(
    const float* __restrict__ pm, const float* __restrict__ ps,
    float2* __restrict__ stats)
{
  const long row = (long)blockIdx.x * 256 + threadIdx.x;
  const float* m = pm + row * 8;
  const float* s = ps + row * 8;
  float mv[8];
  float mm = -3.4e38f;
#pragma unroll
  for (int j = 0; j < 8; ++j) { mv[j] = m[j]; mm = fmaxf(mm, mv[j]); }
  float ss = 0.f;
#pragma unroll
  for (int j = 0; j < 8; ++j) ss += s[j] * __expf(mv[j] - mm);
  stats[row] = make_float2(mm, 1.f / ss);
}

// f32 -> split bf16 (hi + lo), vectorized, grid-stride
__global__ __launch_bounds__(256) void cvt_split(
    const float* __restrict__ in, short* __restrict__ hi, short* __restrict__ lo, long n4)
{
  long i = (long)blockIdx.x * 256 + threadIdx.x;
  const long stride = (long)gridDim.x * 256;
  for (; i < n4; i += stride) {
    f32x4 v = *(const f32x4*)(in + i * 4);
    bf16x4_t h, lw;
#pragma unroll
    for (int q = 0; q < 4; ++q) {
      h[q] = (short)f2bf(v[q]);
      lw[q] = (short)f2bf(v[q] - bf2f((unsigned short)h[q]));
    }
    *(bf16x4_t*)(hi + i * 4) = h;
    *(bf16x4_t*)(lo + i * 4) = lw;
  }
}

// K f32 -> Kh (separate, for E2) + Kcat3 [b][s][Kh|Kl|Kh] (for E1's 3-term)
__global__ __launch_bounds__(256) void cvt_kcat(
    const float* __restrict__ K, short* __restrict__ Kh, short* __restrict__ Kcat)
{
  const long i = (long)blockIdx.x * 256 + threadIdx.x;   // B*S*128 groups of 4
  f32x4 v = *(const f32x4*)(K + i * 4);
  bf16x4_t h, lw;
#pragma unroll
  for (int q = 0; q < 4; ++q) {
    h[q] = (short)f2bf(v[q]);
    lw[q] = (short)f2bf(v[q] - bf2f((unsigned short)h[q]));
  }
  *(bf16x4_t*)(Kh + i * 4) = h;
  const long srow = i >> 7;
  const int c = (int)(i & 127) * 4;
  short* rowp = Kcat + srow * 1536;
  *(bf16x4_t*)(rowp + c) = h;
  *(bf16x4_t*)(rowp + 512 + c) = lw;
  *(bf16x4_t*)(rowp + 1024 + c) = h;
}

// V [B][S][D] f32 -> VT [B][D][S] bf16
__global__ __launch_bounds__(256) void vtrans(
    const float* __restrict__ V, short* __restrict__ TH)
{
  __shared__ float tile[32][33];
  const int b = blockIdx.z;
  const int s0 = blockIdx.x * 32, d0 = blockIdx.y * 32;
  const int tx = threadIdx.x & 31, ty = threadIdx.x >> 5;
  const float* Vb = V + (long)b * SS * DD;
  short* Hb = TH + (long)b * DD * SS;
#pragma unroll
  for (int i = 0; i < 32; i += 8)
    tile[ty + i][tx] = Vb[(long)(s0 + ty + i) * DD + d0 + tx];
  __syncthreads();
#pragma unroll
  for (int i = 0; i < 32; i += 8)
    Hb[(long)(d0 + ty + i) * SS + s0 + tx] = (short)f2bf(tile[tx][ty + i]);
}

// Q2b[b,l,d] = Q2[l,d] + C1[b, map[l], d]  -> bf16 hi
__global__ __launch_bounds__(256) void make_q2b(
    const float* __restrict__ Q2f, const float* __restrict__ C1,
    const int* __restrict__ map, short* __restrict__ Oh)
{
  const long idx = (long)blockIdx.x * 256 + threadIdx.x;
  const long per_b = (long)NLAB * (DD / 4);
  const int b = (int)(idx / per_b);
  const long rem = idx - (long)b * per_b;
  const int ll = (int)(rem >> 7);
  const int dd = (int)(rem & 127) << 2;
  const int cat = map[ll];
  f32x4 qv = *(const f32x4*)(Q2f + (long)ll * DD + dd);
  f32x4 cv = *(const f32x4*)(C1 + ((long)b * NCAT + cat) * DD + dd);
  bf16x4_t h;
#pragma unroll
  for (int q = 0; q < 4; ++q) h[q] = (short)f2bf(qv[q] + cv[q]);
  *(bf16x4_t*)(Oh + idx * 4) = h;
}

extern "C" void kernel_launch(void* const* d_in, const int* in_sizes, int n_in,
                              void* d_out, int out_size, void* d_ws, size_t ws_size,
                              hipStream_t stream)
{
  const float* K    = (const float*)d_in[0];
  const float* V    = (const float*)d_in[1];
  const int*   map  = (const int*)d_in[2];
  const float* Q1w  = (const float*)d_in[3];
  const float* Q2w  = (const float*)d_in[4];
  const float* mapw = (const float*)d_in[5];
  const float* mapb = (const float*)d_in[6];

  float* out = (float*)d_out;
  const long C2SZ = (long)BB * NLAB * DD;
  float* outC2 = out;
  float* outE2 = out + C2SZ;                  // [B][NLAB][SS] f32 (E1 parks here too)

  char* ws = (char*)d_ws;
  short* Kh    = (short*)ws; ws += (long)BB * SS * DD * 2;
  short* Kcat  = (short*)ws; ws += (long)BB * SS * 1536 * 2;     // [b][s][Kh|Kl|Kh]
  short* VTh   = (short*)ws; ws += (long)BB * DD * SS * 2;
  short* Qwh   = (short*)ws; ws += (long)(NCAT + NLAB) * DD * 2;  // input embeds hi
  short* Qwl   = (short*)ws; ws += (long)(NCAT + NLAB) * DD * 2;  // input embeds lo
  short* mwh   = (short*)ws; ws += (long)DD * DD * 2;
  short* mwl   = (short*)ws; ws += (long)DD * DD * 2;
  float* Qall  = (float*)ws; ws += (long)(NCAT + NLAB) * DD * 4;  // projected f32
  short* Qcat  = (short*)ws; ws += (long)NCAT * 1024 * 2;         // [Q1h|Q1l]
  float* C1    = (float*)ws; ws += (long)BB * NCAT * DD * 4;
  short* Q2bh  = (short*)ws; ws += (long)BB * NLAB * DD * 2;
  float* pm    = (float*)ws; ws += (long)BB * NLAB * 8 * 4;
  float* psum  = (float*)ws; ws += (long)BB * NLAB * 8 * 4;
  float* pm1   = (float*)ws; ws += (long)BB * NCAT * 8 * 4;
  float* ps1   = (float*)ws; ws += (long)BB * NCAT * 8 * 4;
  float2* stats  = (float2*)ws; ws += (long)BB * NLAB * 8;
  float2* stats1 = (float2*)ws;

  // 1. conversions + V transpose
  cvt_kcat<<<(int)((long)BB * SS * DD / 4 / 256), 256, 0, stream>>>(K, Kh, Kcat);
  vtrans<<<dim3(SS / 32, DD / 32, BB), 256, 0, stream>>>(V, VTh);
  cvt_split<<<512, 256, 0, stream>>>(Q1w, Qwh, Qwl, (long)NCAT * DD / 4);
  cvt_split<<<2048, 256, 0, stream>>>(Q2w, Qwh + (long)NCAT * DD, Qwl + (long)NCAT * DD,
                                      (long)NLAB * DD / 4);
  cvt_split<<<256, 256, 0, stream>>>(mapw, mwh, mwl, (long)DD * DD / 4);

  // 2. Q projection (fp32-accurate); epilogue also emits Qcat=[Q1h|Q1l]
  gemm_nt_split<1, 1><<<dim3((NCAT + NLAB) / 128, DD / 128, 1), 256, 0, stream>>>(
      Qwh, Qwl, mwh, mwl, Qall, Qcat, mapb, NCAT + NLAB, DD, DD);

  // 3. E1 = 3-term split Q1 @ K^T (KK=1536: Qh*Kh + Qh*Kl + Ql*Kh) + stats
  gemm_qk<1536><<<dim3(NCAT / 256, SS / 256, BB), 512, 0, stream>>>(
      Qcat, 0L, Kcat, outE2, pm1, ps1, NCAT);
  stats_combine<<<BB * NCAT / 256, 256, 0, stream>>>(pm1, ps1, stats1);

  // 4. C1 = softmax(E1) @ V (P generated on the fly)
  gemm_pv<<<dim3(NCAT / 256, DD / 256, BB), 512, 0, stream>>>(
      outE2, stats1, VTh, C1, NCAT);

  // 5. Q2b = Q2 + C1[map] -> bf16 hi
  make_q2b<<<(int)((long)BB * NLAB * DD / 4 / 256), 256, 0, stream>>>(
      Qall + (long)NCAT * DD, C1, map, Q2bh);

  // 6. E2 = Q2bh @ Kh^T + fused stats
  gemm_qk<512><<<dim3(NLAB / 256, SS / 256, BB), 512, 0, stream>>>(
      Q2bh, (long)NLAB * DD, Kh, outE2, pm, psum, NLAB);
  stats_combine<<<BB * NLAB / 256, 256, 0, stream>>>(pm, psum, stats);

  // 7. C2 = softmax(E2) @ V -> d_out
  gemm_pv<<<dim3(NLAB / 256, DD / 256, BB), 512, 0, stream>>>(
      outE2, stats, VTh, outC2, NLAB);
}

// Round 11
// 787.556 us; speedup vs baseline: 1.0528x; 1.0528x over previous
//
#include <hip/hip_runtime.h>
#include <hip/hip_bf16.h>
#include <stdint.h>

// Problem constants
#define BB 8
#define SS 2048
#define DD 512
#define NCAT 1024
#define NLAB 8192

typedef short bf16x8 __attribute__((ext_vector_type(8)));
typedef short bf16x4_t __attribute__((ext_vector_type(4)));
typedef float f32x4 __attribute__((ext_vector_type(4)));

#define BAR() do { asm volatile("" ::: "memory"); __builtin_amdgcn_s_barrier(); asm volatile("" ::: "memory"); } while (0)

__device__ __forceinline__ unsigned short f2bf(float f) {
  union { float f; unsigned int u; } v; v.f = f;
  unsigned int u = v.u;
  return (unsigned short)((u + 0x7fffu + ((u >> 16) & 1u)) >> 16);
}
__device__ __forceinline__ float bf2f(unsigned short h) {
  union { unsigned int u; float f; } v; v.u = ((unsigned int)h) << 16;
  return v.f;
}

__device__ __forceinline__ void gload_lds16(const void* g, void* l) {
  __builtin_amdgcn_global_load_lds(
      (const __attribute__((address_space(1))) unsigned int*)g,
      (__attribute__((address_space(3))) unsigned int*)l, 16, 0, 0);
}

// ===========================================================================
// E2 GEMM, 8-phase deep pipeline: E[b] = A[b] (Mx512) @ Kh[b] (2048x512)^T
// 256x256 tile, BK=32, 8 waves (2Mx4N), 3-buffer LDS rotation, counted
// vmcnt(4), T2 swizzle, T5 setprio. Fused softmax partial-stats epilogue.
// ===========================================================================
__global__ __launch_bounds__(512, 2) void gemm_qk512(
    const short* __restrict__ A, long sA,
    const short* __restrict__ Bc,           // [B][SS][512] bf16
    float* __restrict__ E, float* __restrict__ pm, float* __restrict__ ps,
    int M)
{
  constexpr int NK = 16;
  __shared__ __align__(16) char lds[3 * 32768];  // 3 bufs x (A 16KB + B 16KB)
  const int t = threadIdx.x;
  const int w = t >> 6, lane = t & 63;
  const int r = lane & 15, g = lane >> 4;
  const int wm = w >> 2, wn = w & 3;            // 2 x 4 wave grid
  const int m0 = blockIdx.x * 256, n0 = blockIdx.y * 256;
  const int b = blockIdx.z;
  const short* Ab = A + (long)b * sA;
  const short* Bb = Bc + (long)b * SS * DD;

  int offA[8], offB[4];
#pragma unroll
  for (int i = 0; i < 8; ++i) {
    int row = wm * 128 + i * 16 + r;
    int grp = row >> 1, slot = ((row & 1) << 2) | g;
    offA[i] = grp * 128 + (slot ^ (grp & 7)) * 16;
  }
#pragma unroll
  for (int j = 0; j < 4; ++j) {
    int row = wn * 64 + j * 16 + r;
    int grp = row >> 1, slot = ((row & 1) << 2) | g;
    offB[j] = grp * 128 + (slot ^ (grp & 7)) * 16;
  }

  // staging source coords (inverse swizzle; LDS dest stays linear)
  int srow[2], scol[2];
#pragma unroll
  for (int ld = 0; ld < 2; ++ld) {
    int ch = ld * 512 + t;
    int grp = ch >> 3, sl2 = (ch & 7) ^ (grp & 7);
    srow[ld] = grp * 2 + (sl2 >> 2);
    scol[ld] = (sl2 & 3) * 8;
  }

  auto stageA = [&](int kt, int buf) {
    const long kb = (long)(kt * 32);
#pragma unroll
    for (int ld = 0; ld < 2; ++ld)
      gload_lds16(Ab + (long)(m0 + srow[ld]) * DD + kb + scol[ld],
                  lds + buf * 32768 + (ld * 512 + t) * 16);
  };
  auto stageB = [&](int kt, int buf) {
    const long kb = (long)(kt * 32);
#pragma unroll
    for (int ld = 0; ld < 2; ++ld)
      gload_lds16(Bb + (long)(n0 + srow[ld]) * DD + kb + scol[ld],
                  lds + buf * 32768 + 16384 + (ld * 512 + t) * 16);
  };

  f32x4 acc[8][4] = {};

  // prologue: stage K-tiles 0,1; wait tile 0 (vmcnt(4): tile 1 stays in flight)
  stageA(0, 0); stageB(0, 0);
  stageA(1, 1); stageB(1, 1);
  asm volatile("s_waitcnt vmcnt(4)" ::: "memory");
  BAR();

  int cur = 0;
#pragma unroll 1
  for (int kt = 0; kt < NK; ++kt) {
    const char* bA = lds + cur * 32768;
    const char* bB = bA + 16384;
    const int nxt = (cur == 0) ? 2 : cur - 1;  // (kt+2)%3

    bf16x8 av[4], av2[4], bv[4];
    // -------- phase A: reads + stage-A --------
#pragma unroll
    for (int j = 0; j < 4; ++j) bv[j] = *(const bf16x8*)(bB + offB[j]);
#pragma unroll
    for (int i = 0; i < 4; ++i) av[i] = *(const bf16x8*)(bA + offA[i]);
    if (kt + 2 < NK) stageA(kt + 2, nxt);
    BAR();
    __builtin_amdgcn_s_setprio(1);
#pragma unroll
    for (int i = 0; i < 4; ++i)
#pragma unroll
      for (int j = 0; j < 4; ++j)
        acc[i][j] = __builtin_amdgcn_mfma_f32_16x16x32_bf16(av[i], bv[j], acc[i][j], 0, 0, 0);
    __builtin_amdgcn_s_setprio(0);
    BAR();
    // -------- phase B: reads + stage-B --------
#pragma unroll
    for (int i = 0; i < 4; ++i) av2[i] = *(const bf16x8*)(bA + offA[4 + i]);
    if (kt + 2 < NK) stageB(kt + 2, nxt);
    BAR();
    __builtin_amdgcn_s_setprio(1);
#pragma unroll
    for (int i = 0; i < 4; ++i)
#pragma unroll
      for (int j = 0; j < 4; ++j)
        acc[4 + i][j] = __builtin_amdgcn_mfma_f32_16x16x32_bf16(av2[i], bv[j], acc[4 + i][j], 0, 0, 0);
    __builtin_amdgcn_s_setprio(0);
    // -------- boundary: tile kt+1 must have landed --------
    if (kt < NK - 1) {
      if (kt == NK - 2) asm volatile("s_waitcnt vmcnt(0)" ::: "memory");
      else              asm volatile("s_waitcnt vmcnt(4)" ::: "memory");
    }
    BAR();
    cur = (cur == 2) ? 0 : cur + 1;
  }

  // C write
  float* Cg = E + (long)b * M * SS;
#pragma unroll
  for (int i = 0; i < 8; ++i)
#pragma unroll
    for (int j = 0; j < 4; ++j) {
      const int col = n0 + wn * 64 + j * 16 + r;
#pragma unroll
      for (int q = 0; q < 4; ++q) {
        const int row = m0 + wm * 128 + i * 16 + g * 4 + q;
        Cg[(long)row * SS + col] = acc[i][j][q];
      }
    }

  // barrier before reusing LDS for stats
  BAR();

  // fused partial softmax stats over this block's 256 cols
  float* smax = (float*)lds;            // [256][4]
  float* ssum = (float*)(lds + 4096);
#pragma unroll
  for (int i = 0; i < 8; ++i)
#pragma unroll
    for (int q = 0; q < 4; ++q) {
      float mm = fmaxf(fmaxf(acc[i][0][q], acc[i][1][q]),
                       fmaxf(acc[i][2][q], acc[i][3][q]));
#pragma unroll
      for (int off = 1; off <= 8; off <<= 1) mm = fmaxf(mm, __shfl_xor(mm, off, 64));
      float s = 0.f;
#pragma unroll
      for (int j = 0; j < 4; ++j) s += __expf(acc[i][j][q] - mm);
#pragma unroll
      for (int off = 1; off <= 8; off <<= 1) s += __shfl_xor(s, off, 64);
      if (r == 0) {
        const int rowt = wm * 128 + i * 16 + g * 4 + q;   // 0..255
        smax[rowt * 4 + wn] = mm;
        ssum[rowt * 4 + wn] = s;
      }
    }
  BAR();
  if (t < 256) {
    float m0_ = smax[t * 4 + 0], m1_ = smax[t * 4 + 1];
    float m2_ = smax[t * 4 + 2], m3_ = smax[t * 4 + 3];
    float mm = fmaxf(fmaxf(m0_, m1_), fmaxf(m2_, m3_));
    float s = ssum[t * 4 + 0] * __expf(m0_ - mm) + ssum[t * 4 + 1] * __expf(m1_ - mm)
            + ssum[t * 4 + 2] * __expf(m2_ - mm) + ssum[t * 4 + 3] * __expf(m3_ - mm);
    const long base = ((long)b * M + m0 + t) * 8 + (n0 >> 8);
    pm[base] = mm;
    ps[base] = s;
  }
}

// ===========================================================================
// PV GEMM, 8-phase deep pipeline: C[b] = P[b] (Mx2048) @ VT[b] (512x2048)^T
// P generated on the fly from E f32 + global stats (reg-staged A, swizzled
// ds_write placed after phase-B MFMA). Used for C2 (M=8192) only — small-M
// PV regressed (round 10: 64 blocks = 1/4 GPU).
// ===========================================================================
__global__ __launch_bounds__(512, 2) void gemm_pv(
    const float* __restrict__ E, const float2* __restrict__ stats,
    const short* __restrict__ VT, float* __restrict__ C, int M)
{
  __shared__ __align__(16) char lds[3 * 32768];
  const int t = threadIdx.x;
  const int w = t >> 6, lane = t & 63;
  const int r = lane & 15, g = lane >> 4;
  const int wm = w >> 2, wn = w & 3;
  const int m0 = blockIdx.x * 256, n0 = blockIdx.y * 256;
  const int b = blockIdx.z;
  const float* Eb = E + (long)b * M * SS;
  const short* Bb = VT + (long)b * DD * SS;

  int offA[8], offB[4];
#pragma unroll
  for (int i = 0; i < 8; ++i) {
    int row = wm * 128 + i * 16 + r;
    int grp = row >> 1, slot = ((row & 1) << 2) | g;
    offA[i] = grp * 128 + (slot ^ (grp & 7)) * 16;
  }
#pragma unroll
  for (int j = 0; j < 4; ++j) {
    int row = wn * 64 + j * 16 + r;
    int grp = row >> 1, slot = ((row & 1) << 2) | g;
    offB[j] = grp * 128 + (slot ^ (grp & 7)) * 16;
  }

  // B staging source coords (inverse swizzle; LDS dest linear)
  int srow[2], scol[2];
#pragma unroll
  for (int ld = 0; ld < 2; ++ld) {
    int ch = ld * 512 + t;
    int grp = ch >> 3, sl2 = (ch & 7) ^ (grp & 7);
    srow[ld] = grp * 2 + (sl2 >> 2);
    scol[ld] = (sl2 & 3) * 8;
  }

  // A staging: thread owns row = t>>1, 16 cols starting at (t&1)*16
  const int arow = t >> 1;
  const int ac0 = (t & 1) * 16;
  int wbyte[2];
  {
    const int grp = arow >> 1, cc0 = ac0 >> 3;
#pragma unroll
    for (int ld = 0; ld < 2; ++ld) {
      const int slot = ((arow & 1) << 2) | (cc0 + ld);
      wbyte[ld] = grp * 128 + (slot ^ (grp & 7)) * 16;
    }
  }
  const float2 st = stats[(long)b * M + m0 + arow];
  const float* asrc = Eb + (long)(m0 + arow) * SS + ac0;

  float areg[16];
  auto loadA = [&](int kt) {
    const float* src = asrc + kt * 32;
#pragma unroll
    for (int u = 0; u < 4; ++u)
      *(f32x4*)(areg + u * 4) = *(const f32x4*)(src + u * 4);
  };
  auto writeA = [&](int buf) {
    char* dst = lds + buf * 32768;
#pragma unroll
    for (int ld = 0; ld < 2; ++ld) {
      bf16x8 p;
#pragma unroll
      for (int q = 0; q < 8; ++q)
        p[q] = (short)f2bf(__expf(areg[ld * 8 + q] - st.x) * st.y);
      *(bf16x8*)(dst + wbyte[ld]) = p;
    }
  };
  auto stageB = [&](int kt, int buf) {
    const long kb = (long)(kt * 32);
#pragma unroll
    for (int ld = 0; ld < 2; ++ld)
      gload_lds16(Bb + (long)(n0 + srow[ld]) * SS + kb + scol[ld],
                  lds + buf * 32768 + 16384 + (ld * 512 + t) * 16);
  };

  f32x4 acc[8][4] = {};

  // prologue: tiles 0,1 (A via regs+ds_write, B via gload_lds)
  loadA(0); stageB(0, 0); writeA(0);
  loadA(1); stageB(1, 1); writeA(1);
  asm volatile("s_waitcnt lgkmcnt(0)" ::: "memory");
  BAR();

  int cur = 0;
#pragma unroll 1
  for (int kt = 0; kt < 64; ++kt) {
    const char* bA = lds + cur * 32768;
    const char* bB = bA + 16384;
    const int nxt = (cur == 0) ? 2 : cur - 1;  // (kt+2)%3

    bf16x8 av[4], av2[4], bv[4];
    // -------- phase A: reads + loadA(kt+2) to regs --------
#pragma unroll
    for (int j = 0; j < 4; ++j) bv[j] = *(const bf16x8*)(bB + offB[j]);
#pragma unroll
    for (int i = 0; i < 4; ++i) av[i] = *(const bf16x8*)(bA + offA[i]);
    if (kt + 2 < 64) loadA(kt + 2);
    BAR();
    __builtin_amdgcn_s_setprio(1);
#pragma unroll
    for (int i = 0; i < 4; ++i)
#pragma unroll
      for (int j = 0; j < 4; ++j)
        acc[i][j] = __builtin_amdgcn_mfma_f32_16x16x32_bf16(av[i], bv[j], acc[i][j], 0, 0, 0);
    __builtin_amdgcn_s_setprio(0);
    BAR();
    // -------- phase B: reads + stage-B --------
#pragma unroll
    for (int i = 0; i < 4; ++i) av2[i] = *(const bf16x8*)(bA + offA[4 + i]);
    if (kt + 2 < 64) stageB(kt + 2, nxt);
    BAR();
    __builtin_amdgcn_s_setprio(1);
#pragma unroll
    for (int i = 0; i < 4; ++i)
#pragma unroll
      for (int j = 0; j < 4; ++j)
        acc[4 + i][j] = __builtin_amdgcn_mfma_f32_16x16x32_bf16(av2[i], bv[j], acc[4 + i][j], 0, 0, 0);
    __builtin_amdgcn_s_setprio(0);
    if (kt + 2 < 64) writeA(nxt);   // exp+cvt+ds_write into freed buffer
    // -------- boundary --------
    if (kt == 62) asm volatile("s_waitcnt vmcnt(0)" ::: "memory");
    asm volatile("s_waitcnt lgkmcnt(0)" ::: "memory");
    BAR();
    cur = (cur == 2) ? 0 : cur + 1;
  }

  float* Cg = C + (long)b * M * DD;
#pragma unroll
  for (int i = 0; i < 8; ++i)
#pragma unroll
    for (int j = 0; j < 4; ++j) {
      const int col = n0 + wn * 64 + j * 16 + r;
#pragma unroll
      for (int q = 0; q < 4; ++q) {
        const int row = m0 + wm * 128 + i * 16 + g * 4 + q;
        Cg[(long)row * DD + col] = acc[i][j][q];
      }
    }
}

// ---------------------------------------------------------------------------
// Split-bf16 NT GEMM: C = A*B^T.
// TERMS=3: acc += Al*Bh + Ah*Bl + Ah*Bh (near-fp32). TERMS=1: Ah*Bh only.
// WQ=1: epilogue also writes split bf16 (hi->Qph, lo->Qpl) for rows < NCAT.
// 128x128 tile, BK=32, 4 waves — high-occupancy path for small GEMMs.
// ---------------------------------------------------------------------------
template<int BIAS, int TERMS, int WQ>
__global__ __launch_bounds__(256) void gemm_nt_split(
    const short* __restrict__ Ah, const short* __restrict__ Al,
    const short* __restrict__ Bh, const short* __restrict__ Bl,
    float* __restrict__ C, short* __restrict__ Qph, short* __restrict__ Qpl,
    const float* __restrict__ bias,
    int M, int N, int K, long sA, long sB, long sC)
{
  __shared__ short AsH[128 * 32];
  __shared__ short AsL[TERMS == 3 ? 128 * 32 : 8];
  __shared__ short BsH[128 * 32];
  __shared__ short BsL[TERMS == 3 ? 128 * 32 : 8];
  const int t = threadIdx.x, w = t >> 6, l = t & 63;
  const int r = l & 15, g = l >> 4;
  const int m0 = blockIdx.x * 128, n0 = blockIdx.y * 128;
  const int b = blockIdx.z;
  const short* Ahb = Ah + (long)b * sA;
  const short* Alb = TERMS == 3 ? Al + (long)b * sA : (const short*)0;
  const short* Bhb = Bh + (long)b * sB;
  const short* Blb = TERMS == 3 ? Bl + (long)b * sB : (const short*)0;
  float* Cg = C + (long)b * sC;
  const int wm = (w >> 1) * 64, wn = (w & 1) * 64;
  const int srow = t >> 2, scol = (t & 3) * 8;

  f32x4 acc[4][4] = {};

  const int nk = K >> 5;
  for (int kt = 0; kt < nk; ++kt) {
    const long k0 = (long)(kt << 5);
    const long ga0 = (long)(m0 + srow) * K + k0 + scol;
    const long ga1 = (long)(m0 + srow + 64) * K + k0 + scol;
    const long gb0 = (long)(n0 + srow) * K + k0 + scol;
    const long gb1 = (long)(n0 + srow + 64) * K + k0 + scol;
    gload_lds16(Ahb + ga0, &AsH[w * 512]);
    gload_lds16(Ahb + ga1, &AsH[2048 + w * 512]);
    gload_lds16(Bhb + gb0, &BsH[w * 512]);
    gload_lds16(Bhb + gb1, &BsH[2048 + w * 512]);
    if (TERMS == 3) {
      gload_lds16(Alb + ga0, &AsL[w * 512]);
      gload_lds16(Alb + ga1, &AsL[2048 + w * 512]);
      gload_lds16(Blb + gb0, &BsL[w * 512]);
      gload_lds16(Blb + gb1, &BsL[2048 + w * 512]);
    }
    __syncthreads();
    bf16x8 ah[4], al_[4], bh[4], bl_[4];
#pragma unroll
    for (int i = 0; i < 4; ++i) {
      ah[i]  = *(const bf16x8*)&AsH[(wm + i * 16 + r) * 32 + g * 8];
      bh[i]  = *(const bf16x8*)&BsH[(wn + i * 16 + r) * 32 + g * 8];
      if (TERMS == 3) {
        al_[i] = *(const bf16x8*)&AsL[(wm + i * 16 + r) * 32 + g * 8];
        bl_[i] = *(const bf16x8*)&BsL[(wn + i * 16 + r) * 32 + g * 8];
      }
    }
#pragma unroll
    for (int i = 0; i < 4; ++i)
#pragma unroll
      for (int j = 0; j < 4; ++j) {
        if (TERMS == 3) {
          acc[i][j] = __builtin_amdgcn_mfma_f32_16x16x32_bf16(al_[i], bh[j], acc[i][j], 0, 0, 0);
          acc[i][j] = __builtin_amdgcn_mfma_f32_16x16x32_bf16(ah[i], bl_[j], acc[i][j], 0, 0, 0);
        }
        acc[i][j] = __builtin_amdgcn_mfma_f32_16x16x32_bf16(ah[i], bh[j], acc[i][j], 0, 0, 0);
      }
    __syncthreads();
  }

#pragma unroll
  for (int i = 0; i < 4; ++i)
#pragma unroll
    for (int j = 0; j < 4; ++j) {
      f32x4 v = acc[i][j];
      const int col = n0 + wn + j * 16 + r;
      float bv = 0.f;
      if (BIAS) bv = bias[col];
#pragma unroll
      for (int q = 0; q < 4; ++q) {
        const int row = m0 + wm + i * 16 + g * 4 + q;
        const float val = v[q] + bv;
        Cg[(long)row * N + col] = val;
        if (WQ && row < NCAT) {
          unsigned short h = f2bf(val);
          Qph[(long)row * N + col] = (short)h;
          Qpl[(long)row * N + col] = (short)f2bf(val - bf2f(h));
        }
      }
    }
}

// combine per-256col partials (8 per row) into per-row (max, 1/sum)
__global__ __launch_bounds__(256) void stats_combine(
    const float* __restrict__ pm, const float* __restrict__ ps,
    float2* __restrict__ stats)
{
  const long row = (long)blockIdx.x * 256 + threadIdx.x;
  const float* m = pm + row * 8;
  const float* s = ps + row * 8;
  float mv[8];
  float mm = -3.4e38f;
#pragma unroll
  for (int j = 0; j < 8; ++j) { mv[j] = m[j]; mm = fmaxf(mm, mv[j]); }
  float ss = 0.f;
#pragma unroll
  for (int j = 0; j < 8; ++j) ss += s[j] * __expf(mv[j] - mm);
  stats[row] = make_float2(mm, 1.f / ss);
}

// ---------------------------------------------------------------------------
// Row softmax over 2048 f32 -> bf16 probabilities (hi only).
// ---------------------------------------------------------------------------
__global__ __launch_bounds__(256) void rowsoft_p(
    const float* __restrict__ X, short* __restrict__ Ph)
{
  __shared__ float red[8];
  const long row = blockIdx.x;
  const float* x = X + row * SS;
  const int t = threadIdx.x, w = t >> 6;
  f32x4 v0 = *(const f32x4*)(x + t * 4);
  f32x4 v1 = *(const f32x4*)(x + 1024 + t * 4);
  float m = fmaxf(fmaxf(fmaxf(v0[0], v0[1]), fmaxf(v0[2], v0[3])),
                  fmaxf(fmaxf(v1[0], v1[1]), fmaxf(v1[2], v1[3])));
#pragma unroll
  for (int off = 32; off; off >>= 1) m = fmaxf(m, __shfl_xor(m, off, 64));
  if ((t & 63) == 0) red[w] = m;
  __syncthreads();
  m = fmaxf(fmaxf(red[0], red[1]), fmaxf(red[2], red[3]));
  float s = 0.f;
#pragma unroll
  for (int i = 0; i < 4; ++i) { v0[i] = __expf(v0[i] - m); s += v0[i]; }
#pragma unroll
  for (int i = 0; i < 4; ++i) { v1[i] = __expf(v1[i] - m); s += v1[i]; }
#pragma unroll
  for (int off = 32; off; off >>= 1) s += __shfl_xor(s, off, 64);
  if ((t & 63) == 0) red[4 + w] = s;
  __syncthreads();
  s = red[4] + red[5] + red[6] + red[7];
  const float inv = 1.f / s;
  bf16x4_t h0, h1;
#pragma unroll
  for (int i = 0; i < 4; ++i) {
    h0[i] = (short)f2bf(v0[i] * inv);
    h1[i] = (short)f2bf(v1[i] * inv);
  }
  *(bf16x4_t*)(Ph + row * SS + t * 4) = h0;
  *(bf16x4_t*)(Ph + row * SS + 1024 + t * 4) = h1;
}

// f32 -> split bf16 (hi + lo), vectorized, grid-stride
__global__ __launch_bounds__(256) void cvt_split(
    const float* __restrict__ in, short* __restrict__ hi, short* __restrict__ lo, long n4)
{
  long i = (long)blockIdx.x * 256 + threadIdx.x;
  const long stride = (long)gridDim.x * 256;
  for (; i < n4; i += stride) {
    f32x4 v = *(const f32x4*)(in + i * 4);
    bf16x4_t h, lw;
#pragma unroll
    for (int q = 0; q < 4; ++q) {
      h[q] = (short)f2bf(v[q]);
      lw[q] = (short)f2bf(v[q] - bf2f((unsigned short)h[q]));
    }
    *(bf16x4_t*)(hi + i * 4) = h;
    *(bf16x4_t*)(lo + i * 4) = lw;
  }
}

// V [B][S][D] f32 -> VT [B][D][S] bf16
__global__ __launch_bounds__(256) void vtrans(
    const float* __restrict__ V, short* __restrict__ TH)
{
  __shared__ float tile[32][33];
  const int b = blockIdx.z;
  const int s0 = blockIdx.x * 32, d0 = blockIdx.y * 32;
  const int tx = threadIdx.x & 31, ty = threadIdx.x >> 5;
  const float* Vb = V + (long)b * SS * DD;
  short* Hb = TH + (long)b * DD * SS;
#pragma unroll
  for (int i = 0; i < 32; i += 8)
    tile[ty + i][tx] = Vb[(long)(s0 + ty + i) * DD + d0 + tx];
  __syncthreads();
#pragma unroll
  for (int i = 0; i < 32; i += 8)
    Hb[(long)(d0 + ty + i) * SS + s0 + tx] = (short)f2bf(tile[tx][ty + i]);
}

// Q2b[b,l,d] = Q2[l,d] + C1[b, map[l], d]  -> bf16 hi
__global__ __launch_bounds__(256) void make_q2b(
    const float* __restrict__ Q2f, const float* __restrict__ C1,
    const int* __restrict__ map, short* __restrict__ Oh)
{
  const long idx = (long)blockIdx.x * 256 + threadIdx.x;
  const long per_b = (long)NLAB * (DD / 4);
  const int b = (int)(idx / per_b);
  const long rem = idx - (long)b * per_b;
  const int ll = (int)(rem >> 7);
  const int dd = (int)(rem & 127) << 2;
  const int cat = map[ll];
  f32x4 qv = *(const f32x4*)(Q2f + (long)ll * DD + dd);
  f32x4 cv = *(const f32x4*)(C1 + ((long)b * NCAT + cat) * DD + dd);
  bf16x4_t h;
#pragma unroll
  for (int q = 0; q < 4; ++q) h[q] = (short)f2bf(qv[q] + cv[q]);
  *(bf16x4_t*)(Oh + idx * 4) = h;
}

extern "C" void kernel_launch(void* const* d_in, const int* in_sizes, int n_in,
                              void* d_out, int out_size, void* d_ws, size_t ws_size,
                              hipStream_t stream)
{
  const float* K    = (const float*)d_in[0];
  const float* V    = (const float*)d_in[1];
  const int*   map  = (const int*)d_in[2];
  const float* Q1w  = (const float*)d_in[3];
  const float* Q2w  = (const float*)d_in[4];
  const float* mapw = (const float*)d_in[5];
  const float* mapb = (const float*)d_in[6];

  float* out = (float*)d_out;
  const long C2SZ = (long)BB * NLAB * DD;
  float* outC2 = out;
  float* outE2 = out + C2SZ;                  // [B][NLAB][SS] f32 (E1 parks here too)

  char* ws = (char*)d_ws;
  short* Kh    = (short*)ws; ws += (long)BB * SS * DD * 2;
  short* Kl    = (short*)ws; ws += (long)BB * SS * DD * 2;
  short* VTh   = (short*)ws; ws += (long)BB * DD * SS * 2;
  short* Qwh   = (short*)ws; ws += (long)(NCAT + NLAB) * DD * 2;  // input embeds hi
  short* Qwl   = (short*)ws; ws += (long)(NCAT + NLAB) * DD * 2;  // input embeds lo
  short* mwh   = (short*)ws; ws += (long)DD * DD * 2;
  short* mwl   = (short*)ws; ws += (long)DD * DD * 2;
  float* Qall  = (float*)ws; ws += (long)(NCAT + NLAB) * DD * 4;  // projected f32
  short* Qph   = (short*)ws; ws += (long)NCAT * DD * 2;           // projected Q1 hi
  short* Qpl   = (short*)ws; ws += (long)NCAT * DD * 2;           // projected Q1 lo
  short* A1h   = (short*)ws; ws += (long)BB * NCAT * SS * 2;
  float* C1    = (float*)ws; ws += (long)BB * NCAT * DD * 4;
  short* Q2bh  = (short*)ws; ws += (long)BB * NLAB * DD * 2;
  float* pm    = (float*)ws; ws += (long)BB * NLAB * 8 * 4;
  float* psum  = (float*)ws; ws += (long)BB * NLAB * 8 * 4;
  float2* stats = (float2*)ws;

  // 1. conversions + V transpose
  cvt_split<<<2048, 256, 0, stream>>>(K, Kh, Kl, (long)BB * SS * DD / 4);
  vtrans<<<dim3(SS / 32, DD / 32, BB), 256, 0, stream>>>(V, VTh);
  cvt_split<<<512, 256, 0, stream>>>(Q1w, Qwh, Qwl, (long)NCAT * DD / 4);
  cvt_split<<<2048, 256, 0, stream>>>(Q2w, Qwh + (long)NCAT * DD, Qwl + (long)NCAT * DD,
                                      (long)NLAB * DD / 4);
  cvt_split<<<256, 256, 0, stream>>>(mapw, mwh, mwl, (long)DD * DD / 4);

  // 2. Q projection (fp32-accurate); epilogue emits split bf16 Q1 directly
  gemm_nt_split<1, 3, 1><<<dim3((NCAT + NLAB) / 128, DD / 128, 1), 256, 0, stream>>>(
      Qwh, Qwl, mwh, mwl, Qall, Qph, Qpl, mapb, NCAT + NLAB, DD, DD, 0, 0, 0);

  // 3. E1 = Q1 @ K^T (3-term split, 128^2 high-occupancy) -> E2 region
  gemm_nt_split<0, 3, 0><<<dim3(NCAT / 128, SS / 128, BB), 256, 0, stream>>>(
      Qph, Qpl, Kh, Kl, outE2, (short*)0, (short*)0, (const float*)0,
      NCAT, SS, DD, 0, (long)SS * DD, (long)NCAT * SS);

  // 4. A1 = softmax(E1) -> bf16
  rowsoft_p<<<BB * NCAT, 256, 0, stream>>>(outE2, A1h);

  // 5. C1 = A1 @ V (single-term, 128^2 high-occupancy)
  gemm_nt_split<0, 1, 0><<<dim3(NCAT / 128, DD / 128, BB), 256, 0, stream>>>(
      A1h, (const short*)0, VTh, (const short*)0, C1, (short*)0, (short*)0,
      (const float*)0, NCAT, DD, SS, (long)NCAT * SS, (long)DD * SS, (long)NCAT * DD);

  // 6. Q2b = Q2 + C1[map] -> bf16 hi
  make_q2b<<<(int)((long)BB * NLAB * DD / 4 / 256), 256, 0, stream>>>(
      Qall + (long)NCAT * DD, C1, map, Q2bh);

  // 7. E2 = Q2bh @ Kh^T (256^2 8-phase) + fused stats
  gemm_qk512<<<dim3(NLAB / 256, SS / 256, BB), 512, 0, stream>>>(
      Q2bh, (long)NLAB * DD, Kh, outE2, pm, psum, NLAB);
  stats_combine<<<BB * NLAB / 256, 256, 0, stream>>>(pm, psum, stats);

  // 8. C2 = softmax(E2) @ V -> d_out (256^2 8-phase PV)
  gemm_pv<<<dim3(NLAB / 256, DD / 256, BB), 512, 0, stream>>>(
      outE2, stats, VTh, outC2, NLAB);
}